// Round 10
// baseline (701.675 us; speedup 1.0000x reference)
//
#include <hip/hip_runtime.h>
#include <cstddef>

#define NN 50000      // nodes
#define NE 800000     // edges (without self loops)
#define NG 250        // graphs
#define TT 200        // nodes per graph / LSTM steps
#define DD 128        // feature dim
#define GH 512        // 4*LSTM_H
#define NEG_SLOPE 0.2f
#define NCHUNK 4
#define CLEN 50       // TT / NCHUNK (fallback path)
#define CAP 128       // per-wave LDS edge cache

static __device__ __forceinline__ float fsig(float x) { return 1.0f / (1.0f + __expf(-x)); }
static __device__ __forceinline__ float ftanh(float x) {
    float e = __expf(2.0f * x);
    return 1.0f - 2.0f / (e + 1.0f);
}

// async global->LDS, 16B per lane. dst is the wave-uniform base; HW writes dst+lane*16.
static __device__ __forceinline__ void gll16(const float* src, float* ldsdst) {
    __builtin_amdgcn_global_load_lds(
        (const __attribute__((address_space(1))) void*)src,
        (__attribute__((address_space(3))) void*)ldsdst, 16, 0, 0);
}

// ------------------------- fused init: cnt=1 (NN), gstart=NN (NG+1) ----------
__global__ void k_init(int* cnt, int* gstart, int n, int ng1) {
    int i = blockIdx.x * 256 + threadIdx.x;
    if (i < n) cnt[i] = 1;
    if (i < ng1) gstart[i] = n;
}

// ------------------------- both weight transposes, one launch ----------------
__global__ void k_transpose2(const float* __restrict__ inA, float* __restrict__ outA,
                             const float* __restrict__ inB, float* __restrict__ outB) {
    int b = blockIdx.x, k = threadIdx.x;
    if (b < DD) outA[b * DD + k] = inA[k * DD + b];
    else { int n = b - DD; outB[n * DD + k] = inB[k * DD + n]; }
}

// ------------------------- GEMM: C[M,N] = A'[M,128] @ B[N,128]^T (+bias) ---------
// BK=32, 4 K-steps, double-buffered LDS, async global_load_lds staging, one
// barrier per K-step. XOR swizzle on the GLOBAL source column + same XOR on the
// ds_read index. k4 loop stays rolled (spill lesson, r2).
__global__ __launch_bounds__(256) void k_gemm(
    const float* __restrict__ A, const float* __restrict__ B, float* __restrict__ C,
    int M, int N, int t0, int clen, int rowsPerGraph,
    const float* __restrict__ bias1, const float* __restrict__ bias2)
{
    __shared__ float4 As[2][1024];
    __shared__ float4 Bs[2][1024];
    const int tid = threadIdx.x;
    const int wv = tid >> 6;
    const int m0 = blockIdx.x * 128, n0 = blockIdx.y * 128;
    const int tr = tid >> 4, tc = tid & 15;

    float acc[8][8];
    #pragma unroll
    for (int i = 0; i < 8; ++i)
        #pragma unroll
        for (int j = 0; j < 8; ++j) acc[i][j] = 0.f;

    auto stageA = [&](int buf, int k0) {
        #pragma unroll
        for (int it = 0; it < 4; ++it) {
            int f4 = it * 256 + tid;
            int r = f4 >> 3;
            int c4s = (f4 & 7) ^ (r & 7);
            int gr = m0 + r;
            float* dst = (float*)&As[buf][it * 256 + wv * 64];
            if (gr < M) {
                int flat = (gr / clen) * rowsPerGraph + t0 + (gr % clen);
                gll16(A + (size_t)flat * DD + k0 + c4s * 4, dst);
            }
        }
    };
    auto stageB = [&](int buf, int k0) {
        #pragma unroll
        for (int it = 0; it < 4; ++it) {
            int f4 = it * 256 + tid;
            int r = f4 >> 3;
            int c4s = (f4 & 7) ^ (r & 7);
            int gn = n0 + r;
            float* dst = (float*)&Bs[buf][it * 256 + wv * 64];
            if (gn < N) gll16(B + (size_t)gn * DD + k0 + c4s * 4, dst);
        }
    };

    stageA(0, 0); stageB(0, 0);
    __syncthreads();
    int buf = 0;
    const int axor = tr & 7;
    const int bxor = tc & 7;
    for (int ks = 0; ks < 4; ++ks) {
        if (ks < 3) { stageA(buf ^ 1, (ks + 1) * 32); stageB(buf ^ 1, (ks + 1) * 32); }
        const float4* Af = &As[buf][0];
        const float4* Bf = &Bs[buf][0];
        #pragma unroll 1
        for (int k4 = 0; k4 < 8; ++k4) {
            float4 a[8], b[8];
            #pragma unroll
            for (int i = 0; i < 8; ++i) a[i] = Af[(tr + i * 16) * 8 + (k4 ^ axor)];
            #pragma unroll
            for (int j = 0; j < 8; ++j) b[j] = Bf[(tc + j * 16) * 8 + (k4 ^ bxor)];
            #pragma unroll
            for (int i = 0; i < 8; ++i)
                #pragma unroll
                for (int j = 0; j < 8; ++j)
                    acc[i][j] += a[i].x * b[j].x + a[i].y * b[j].y + a[i].z * b[j].z + a[i].w * b[j].w;
        }
        __syncthreads();
        buf ^= 1;
    }

    #pragma unroll
    for (int i = 0; i < 8; ++i) {
        int gr = m0 + tr + i * 16;
        if (gr >= M) continue;
        #pragma unroll
        for (int j = 0; j < 8; ++j) {
            int gn = n0 + tc + j * 16;
            if (gn >= N) continue;
            float v = acc[i][j];
            if (bias1) v += bias1[gn];
            if (bias2) v += bias2[gn];
            C[(size_t)gr * N + gn] = v;
        }
    }
}

// ------------------------- alpha_s / alpha_d -------------------------
__global__ __launch_bounds__(256) void k_alpha(
    const float* __restrict__ h1, const float* __restrict__ a_src, const float* __restrict__ a_dst,
    float* __restrict__ as_out, float* __restrict__ ad_out, int n)
{
    int node = blockIdx.x * 4 + (threadIdx.x >> 6);
    int lane = threadIdx.x & 63;
    if (node >= n) return;
    float2 hv = *(const float2*)(h1 + (size_t)node * DD + 2 * lane);
    float2 av = *(const float2*)(a_src + 2 * lane);
    float2 dv = *(const float2*)(a_dst + 2 * lane);
    float s = hv.x * av.x + hv.y * av.y;
    float d = hv.x * dv.x + hv.y * dv.y;
    #pragma unroll
    for (int off = 1; off < 64; off <<= 1) {
        s += __shfl_xor(s, off);
        d += __shfl_xor(d, off);
    }
    if (lane == 0) { as_out[node] = s; ad_out[node] = d; }
}

// ------------------------- CSR build -------------------------
__global__ void k_hist(const int* __restrict__ ei, int* cnt, int E) {
    int e = blockIdx.x * 256 + threadIdx.x;
    if (e < E) atomicAdd(&cnt[ei[E + e]], 1);
}

__global__ __launch_bounds__(1024) void k_scan(const int* __restrict__ cnt, int* __restrict__ rp,
                                               int* __restrict__ fill, int n) {
    __shared__ int wsum[16];
    __shared__ int totsh;
    __shared__ int carrysh;
    int lane = threadIdx.x & 63, wid = threadIdx.x >> 6;
    if (threadIdx.x == 0) carrysh = 0;
    __syncthreads();
    for (int base = 0; base < n; base += 4096) {
        int idx = base + threadIdx.x * 4;
        int v0 = (idx < n) ? cnt[idx] : 0;
        int v1 = (idx + 1 < n) ? cnt[idx + 1] : 0;
        int v2 = (idx + 2 < n) ? cnt[idx + 2] : 0;
        int v3 = (idx + 3 < n) ? cnt[idx + 3] : 0;
        int s = v0 + v1 + v2 + v3;
        int sc = s;
        #pragma unroll
        for (int off = 1; off < 64; off <<= 1) {
            int t = __shfl_up(sc, off);
            if (lane >= off) sc += t;
        }
        if (lane == 63) wsum[wid] = sc;
        __syncthreads();
        if (threadIdx.x == 0) {
            int run = 0;
            for (int w = 0; w < 16; ++w) { int t = wsum[w]; wsum[w] = run; run += t; }
            totsh = run;
        }
        __syncthreads();
        int ex = carrysh + wsum[wid] + (sc - s);
        if (idx < n)     { rp[idx] = ex;     fill[idx] = ex; }
        ex += v0;
        if (idx + 1 < n) { rp[idx + 1] = ex; fill[idx + 1] = ex; }
        ex += v1;
        if (idx + 2 < n) { rp[idx + 2] = ex; fill[idx + 2] = ex; }
        ex += v2;
        if (idx + 3 < n) { rp[idx + 3] = ex; fill[idx + 3] = ex; }
        __syncthreads();
        if (threadIdx.x == 0) carrysh += totsh;
        __syncthreads();
    }
    if (threadIdx.x == 0) rp[n] = carrysh;
}

__global__ void k_fill(const int* __restrict__ ei, int* fill, int* esrc, int E, int N) {
    int i = blockIdx.x * 256 + threadIdx.x;
    if (i < E) {
        int s = ei[i], d = ei[E + i];
        int slot = atomicAdd(&fill[d], 1);
        esrc[slot] = s;
    } else if (i < E + N) {
        int v = i - E;
        int slot = atomicAdd(&fill[v], 1);
        esrc[slot] = v;
    }
}

// ------------------------- dinv + graph bounds, one launch -------------------
__global__ void k_dinv_bounds(const int* __restrict__ rp, float* dinv,
                              const int* __restrict__ batch, int* gstart, int n) {
    int i = blockIdx.x * 256 + threadIdx.x;
    if (i >= n) return;
    dinv[i] = rsqrtf(fmaxf((float)(rp[i + 1] - rp[i]), 1.0f));
    int b = batch[i];
    if (i == 0 || batch[i - 1] != b) gstart[b] = i;
}

__global__ void k_glen(const int* __restrict__ gstart, int* gcount, int ng) {
    int g = blockIdx.x * 256 + threadIdx.x;
    if (g >= ng) return;
    int c = gstart[g + 1] - gstart[g];
    gcount[g] = c < 0 ? 0 : c;
}

// ------------------------- GAT aggregation (wave per node) -------------------------
__global__ __launch_bounds__(256) void k_gat(
    const float* __restrict__ h1, const float* __restrict__ as, const float* __restrict__ ad_,
    const int* __restrict__ rp, const int* __restrict__ esrc,
    const float* __restrict__ bias, float* __restrict__ out, int n)
{
    __shared__ float2 ws_sh[4][CAP];   // .x = weight, .y = src (bits)
    int wv = threadIdx.x >> 6;
    int node = blockIdx.x * 4 + wv;
    int lane = threadIdx.x & 63;
    if (node >= n) return;
    int r0 = rp[node], r1 = rp[node + 1];
    int deg = r1 - r0;
    float adv = ad_[node];

    float sum = 0.f;
    for (int base = 0; base < deg; base += 64) {
        int idx = base + lane;
        float ex = 0.f;
        if (idx < deg) {
            int s = esrc[r0 + idx];
            float e = as[s] + adv;
            e = e > 0.f ? e : NEG_SLOPE * e;
            ex = __expf(e);
            if (idx < CAP) ws_sh[wv][idx] = make_float2(ex, __int_as_float(s));
        }
        sum += ex;
    }
    #pragma unroll
    for (int off = 1; off < 64; off <<= 1) sum += __shfl_xor(sum, off);
    float inv = 1.0f / sum;

    int nser = deg < CAP ? deg : CAP;
    int npad = (nser + 7) & ~7;        // deg>=1 (self loop) -> npad>=8
    for (int p = nser + lane; p < npad; p += 64)
        ws_sh[wv][p] = make_float2(0.f, __int_as_float(0));

    const float2* h1p = (const float2*)h1;
    float ax = 0.f, ay = 0.f;
    float wa[8]; float2 va[8];
    #pragma unroll
    for (int u = 0; u < 8; ++u) {
        float2 t = ws_sh[wv][u];
        wa[u] = t.x; va[u] = h1p[(size_t)__float_as_int(t.y) * 64 + lane];
    }
    #pragma unroll 1
    for (int idx = 8; idx < npad; idx += 8) {
        float wb[8]; float2 vb[8];
        #pragma unroll
        for (int u = 0; u < 8; ++u) {
            float2 t = ws_sh[wv][idx + u];
            wb[u] = t.x; vb[u] = h1p[(size_t)__float_as_int(t.y) * 64 + lane];
        }
        #pragma unroll
        for (int u = 0; u < 8; ++u) { ax += wa[u] * va[u].x; ay += wa[u] * va[u].y; }
        #pragma unroll
        for (int u = 0; u < 8; ++u) { wa[u] = wb[u]; va[u] = vb[u]; }
    }
    #pragma unroll
    for (int u = 0; u < 8; ++u) { ax += wa[u] * va[u].x; ay += wa[u] * va[u].y; }

    for (int j = r0 + CAP; j < r1; ++j) {
        int s = esrc[j];
        float e = as[s] + adv;
        e = e > 0.f ? e : NEG_SLOPE * e;
        float w = __expf(e);
        float2 hv = h1p[(size_t)s * 64 + lane];
        ax += w * hv.x;
        ay += w * hv.y;
    }
    float2 bv = *(const float2*)(bias + 2 * lane);
    float2 o;
    o.x = fmaxf(ax * inv + bv.x, 0.f);
    o.y = fmaxf(ay * inv + bv.y, 0.f);
    *(float2*)(out + (size_t)node * DD + 2 * lane) = o;
}

// ------------------------- GCN aggregation + scatter to padded ----------------
__global__ __launch_bounds__(256) void k_gcn(
    const float* __restrict__ h2, const float* __restrict__ dinv,
    const int* __restrict__ rp, const int* __restrict__ esrc,
    const float* __restrict__ bias, const int* __restrict__ batch,
    const int* __restrict__ gstart, float* __restrict__ padded, int n)
{
    __shared__ float2 cs_sh[4][CAP];
    int wv = threadIdx.x >> 6;
    int node = blockIdx.x * 4 + wv;
    int lane = threadIdx.x & 63;
    if (node >= n) return;
    int r0 = rp[node], r1 = rp[node + 1];
    int deg = r1 - r0;
    float dn = dinv[node];

    for (int base = 0; base < deg; base += 64) {
        int idx = base + lane;
        if (idx < deg && idx < CAP) {
            int s = esrc[r0 + idx];
            cs_sh[wv][idx] = make_float2(dinv[s], __int_as_float(s));
        }
    }
    int nser = deg < CAP ? deg : CAP;
    int npad = (nser + 7) & ~7;
    for (int p = nser + lane; p < npad; p += 64)
        cs_sh[wv][p] = make_float2(0.f, __int_as_float(0));

    const float2* h2p = (const float2*)h2;
    float ax = 0.f, ay = 0.f;
    float wa[8]; float2 va[8];
    #pragma unroll
    for (int u = 0; u < 8; ++u) {
        float2 t = cs_sh[wv][u];
        wa[u] = t.x; va[u] = h2p[(size_t)__float_as_int(t.y) * 64 + lane];
    }
    #pragma unroll 1
    for (int idx = 8; idx < npad; idx += 8) {
        float wb[8]; float2 vb[8];
        #pragma unroll
        for (int u = 0; u < 8; ++u) {
            float2 t = cs_sh[wv][idx + u];
            wb[u] = t.x; vb[u] = h2p[(size_t)__float_as_int(t.y) * 64 + lane];
        }
        #pragma unroll
        for (int u = 0; u < 8; ++u) { ax += wa[u] * va[u].x; ay += wa[u] * va[u].y; }
        #pragma unroll
        for (int u = 0; u < 8; ++u) { wa[u] = wb[u]; va[u] = vb[u]; }
    }
    #pragma unroll
    for (int u = 0; u < 8; ++u) { ax += wa[u] * va[u].x; ay += wa[u] * va[u].y; }

    for (int j = r0 + CAP; j < r1; ++j) {
        int s = esrc[j];
        float c = dinv[s];
        float2 hv = h2p[(size_t)s * 64 + lane];
        ax += c * hv.x;
        ay += c * hv.y;
    }
    int g = batch[node];
    if (g < 0 || g >= NG) return;
    int p = node - gstart[g];
    if (p < 0 || p >= TT) return;
    float2 bv = *(const float2*)(bias + 2 * lane);
    float2 o;
    o.x = fmaxf(ax * dn + bv.x, 0.f);
    o.y = fmaxf(ay * dn + bv.y, 0.f);
    *(float2*)(padded + ((size_t)g * TT + p) * DD + 2 * lane) = o;
}

// ------------------------- LSTM: unit-per-lane, in-wave K reduce ----------------
// Wave w owns units 16w..16w+15. Lane l: unit un=16w+(l&15), K-quarter ks=l>>4.
// Each lane computes ALL FOUR gate rows of its unit over its K-quarter (128 weight
// VGPRs), then 2 shfl_xor (16,32) complete the dots IN-WAVE. Every lane holds
// {i,f,g,o} -> activation computed redundantly x4 (c,h replicated). Lanes l<16
// write the 16 new h values. ONE barrier per step; no part[] LDS exchange.
// h_sh[4][40]: pad 8 => segment bases hit banks {0,8,16,24} (conflict-free).
__global__ __launch_bounds__(512) void k_lstm(
    const float* __restrict__ xw,     // [NG*clen, 512], includes b_ih+b_hh
    const float* __restrict__ Whh,    // [512,128]
    const int* __restrict__ glen,
    float* __restrict__ hstate, float* __restrict__ cstate,
    float* __restrict__ grep, int t0, int clen)
{
    const int g = blockIdx.x, tid = threadIdx.x;
    __shared__ __align__(16) float h_sh[4][40];

    const int w  = tid >> 6;       // wave 0..7
    const int l  = tid & 63;
    const int un = 16 * w + (l & 15);   // unit owned by this lane
    const int ks = l >> 4;              // K-quarter 0..3

    // weights: wreg[q][i] = Whh[(q*128+un)*128 + ks*32 + 4i .. +3]
    float4 wreg[4][8];
    #pragma unroll
    for (int q = 0; q < 4; ++q)
        #pragma unroll
        for (int i = 0; i < 8; ++i)
            wreg[q][i] = *(const float4*)(Whh + (size_t)(q * DD + un) * DD + ks * 32 + i * 4);

    float creg = 0.f, hn = 0.f;
    if (t0 == 0) {
        if (tid < DD) h_sh[tid >> 5][tid & 31] = 0.f;
    } else {
        creg = cstate[g * DD + un];
        hn   = hstate[g * DD + un];
        if (l < 16) h_sh[un >> 5][un & 31] = hn;
    }
    int take = glen[g] - 1;
    if (take < 0) take = 0;
    if (take > TT - 1) take = TT - 1;
    __syncthreads();

    const float* xb = xw + (size_t)g * clen * GH + un;
    float xq0 = xb[0], xq1 = xb[DD], xq2 = xb[2 * DD], xq3 = xb[3 * DD];

    for (int t = t0; t < t0 + clen; ++t) {
        int rel = t - t0;
        // full-step-ahead prefetch of next xw
        float xn0 = 0.f, xn1 = 0.f, xn2 = 0.f, xn3 = 0.f;
        if (rel + 1 < clen) {
            const float* xr = xb + (size_t)(rel + 1) * GH;
            xn0 = xr[0]; xn1 = xr[DD]; xn2 = xr[2 * DD]; xn3 = xr[3 * DD];
        }
        // K-quarter of h (broadcast within each 16-lane group, banks disjoint)
        float4 hseg[8];
        #pragma unroll
        for (int i = 0; i < 8; ++i) hseg[i] = *(const float4*)(&h_sh[ks][i * 4]);
        float p0 = 0.f, p1 = 0.f, p2 = 0.f, p3 = 0.f;
        #pragma unroll
        for (int i = 0; i < 8; ++i) {
            float4 h4 = hseg[i];
            p0 += h4.x * wreg[0][i].x + h4.y * wreg[0][i].y + h4.z * wreg[0][i].z + h4.w * wreg[0][i].w;
            p1 += h4.x * wreg[1][i].x + h4.y * wreg[1][i].y + h4.z * wreg[1][i].z + h4.w * wreg[1][i].w;
            p2 += h4.x * wreg[2][i].x + h4.y * wreg[2][i].y + h4.z * wreg[2][i].z + h4.w * wreg[2][i].w;
            p3 += h4.x * wreg[3][i].x + h4.y * wreg[3][i].y + h4.z * wreg[3][i].z + h4.w * wreg[3][i].w;
        }
        // in-wave K reduce: lanes l, l^16, l^32 (+l^48) share the same unit
        p0 += __shfl_xor(p0, 16); p1 += __shfl_xor(p1, 16);
        p2 += __shfl_xor(p2, 16); p3 += __shfl_xor(p3, 16);
        p0 += __shfl_xor(p0, 32); p1 += __shfl_xor(p1, 32);
        p2 += __shfl_xor(p2, 32); p3 += __shfl_xor(p3, 32);
        // activation (replicated x4 per unit)
        float gi = p0 + xq0, gf = p1 + xq1, gg = p2 + xq2, go = p3 + xq3;
        creg = fsig(gf) * creg + fsig(gi) * ftanh(gg);
        hn = fsig(go) * ftanh(creg);
        if (l < 16) {
            h_sh[un >> 5][un & 31] = hn;
            if (t == take) grep[g * DD + un] = hn;
        }
        xq0 = xn0; xq1 = xn1; xq2 = xn2; xq3 = xn3;
        __syncthreads();
    }
    if (l < 16) { hstate[g * DD + un] = hn; cstate[g * DD + un] = creg; }
}

// ------------------------- FC -------------------------
__global__ void k_fc(const float* __restrict__ grep, const float* __restrict__ Wfc,
                     const float* __restrict__ bfc, float* __restrict__ out, int G) {
    int i = blockIdx.x * 256 + threadIdx.x;
    if (i >= G * 2) return;
    int g = i >> 1, o = i & 1;
    float acc = bfc[o];
    for (int d = 0; d < DD; ++d) acc += grep[g * DD + d] * Wfc[d * 2 + o];
    out[i] = acc;
}

// ------------------------- host launch -------------------------
extern "C" void kernel_launch(void* const* d_in, const int* in_sizes, int n_in,
                              void* d_out, int out_size, void* d_ws, size_t ws_size,
                              hipStream_t stream) {
    const float* x     = (const float*)d_in[0];
    const int*   ei    = (const int*)d_in[1];
    const int*   batch = (const int*)d_in[2];
    const float* Wgat  = (const float*)d_in[3];
    const float* a_src = (const float*)d_in[4];
    const float* a_dst = (const float*)d_in[5];
    const float* b_gat = (const float*)d_in[6];
    const float* Wgcn  = (const float*)d_in[7];
    const float* b_gcn = (const float*)d_in[8];
    const float* Wih   = (const float*)d_in[9];   // [512,128]
    const float* Whh   = (const float*)d_in[10];  // [512,128]
    const float* b_ih  = (const float*)d_in[11];
    const float* b_hh  = (const float*)d_in[12];
    const float* Wfc   = (const float*)d_in[13];
    const float* b_fc  = (const float*)d_in[14];
    float* out = (float*)d_out;

    float* ws = (float*)d_ws;
    const size_t F = (size_t)NN * DD;  // 6.4M floats
    float* h1 = ws;
    float* h2 = ws;
    float* xwChunk = ws;
    float* gato   = ws + F;
    float* padded = ws + F;
    size_t off = 2 * F;
    float* alpha_s = ws + off; off += 50048;
    float* alpha_d = ws + off; off += 50048;
    float* dinv    = ws + off; off += 50048;
    int*   cnt     = (int*)(ws + off); off += 50048;
    int*   rp      = (int*)(ws + off); off += 50056;
    int*   fill    = (int*)(ws + off); off += 50048;
    int*   esrc    = (int*)(ws + off); off += 850048;
    int*   gcount  = (int*)(ws + off); off += 256;
    int*   gstart  = (int*)(ws + off); off += 256;
    float* grep    = ws + off; off += 32000;
    float* hstate  = ws + off; off += 32000;
    float* cstate  = ws + off; off += 32000;
    float* WgatT   = ws + off; off += 16384;
    float* WgcnT   = ws + off; off += 16384;
    const size_t xwBigFloats = (size_t)NG * TT * GH;   // 25.6M floats
    float* xwBig = ws + off;
    const bool big = ws_size >= (off + xwBigFloats) * sizeof(float);

    // 1. transpose both weights
    k_transpose2<<<256, 128, 0, stream>>>(Wgat, WgatT, Wgcn, WgcnT);

    // 2. h1 = x @ W_gat
    k_gemm<<<dim3(391, 1), 256, 0, stream>>>(x, WgatT, h1, NN, DD, 0, TT, TT, nullptr, nullptr);

    // 3. alpha
    k_alpha<<<12500, 256, 0, stream>>>(h1, a_src, a_dst, alpha_s, alpha_d, NN);

    // 4. CSR build + graph bounds
    k_init<<<196, 256, 0, stream>>>(cnt, gstart, NN, NG + 1);
    k_hist<<<3125, 256, 0, stream>>>(ei, cnt, NE);
    k_scan<<<1, 1024, 0, stream>>>(cnt, rp, fill, NN);
    k_fill<<<3321, 256, 0, stream>>>(ei, fill, esrc, NE, NN);
    k_dinv_bounds<<<196, 256, 0, stream>>>(rp, dinv, batch, gstart, NN);
    k_glen<<<1, 256, 0, stream>>>(gstart, gcount, NG);

    // 5. GAT aggregation -> gato
    k_gat<<<12500, 256, 0, stream>>>(h1, alpha_s, alpha_d, rp, esrc, b_gat, gato, NN);

    // 6. h2 = gato @ W_gcn
    k_gemm<<<dim3(391, 1), 256, 0, stream>>>(gato, WgcnT, h2, NN, DD, 0, TT, TT, nullptr, nullptr);

    // 7. GCN aggregation -> padded
    k_gcn<<<12500, 256, 0, stream>>>(h2, dinv, rp, esrc, b_gcn, batch, gstart, padded, NN);

    // 8. LSTM
    if (big) {
        k_gemm<<<dim3(391, 4), 256, 0, stream>>>(padded, Wih, xwBig, NG * TT, GH,
                                                 0, TT, TT, b_ih, b_hh);
        k_lstm<<<NG, 512, 0, stream>>>(xwBig, Whh, gcount, hstate, cstate, grep, 0, TT);
    } else {
        for (int c = 0; c < NCHUNK; ++c) {
            int t0 = c * CLEN;
            k_gemm<<<dim3(98, 4), 256, 0, stream>>>(padded, Wih, xwChunk, NG * CLEN, GH,
                                                    t0, CLEN, TT, b_ih, b_hh);
            k_lstm<<<NG, 512, 0, stream>>>(xwChunk, Whh, gcount, hstate, cstate, grep, t0, CLEN);
        }
    }

    // 9. FC
    k_fc<<<2, 256, 0, stream>>>(grep, Wfc, b_fc, out, NG);
}

// Round 11
// 630.648 us; speedup vs baseline: 1.1126x; 1.1126x over previous
//
#include <hip/hip_runtime.h>
#include <cstddef>

#define NN 50000      // nodes
#define NE 800000     // edges (without self loops)
#define NG 250        // graphs
#define TT 200        // nodes per graph / LSTM steps
#define DD 128        // feature dim
#define GH 512        // 4*LSTM_H
#define NEG_SLOPE 0.2f
#define NCHUNK 4
#define CLEN 50       // TT / NCHUNK (fallback path)
#define CAP 128       // per-wave LDS edge cache
#define PSTRIDE 136   // 136 % 32 == 8 -> phase-B reads max 2-way (free)

static __device__ __forceinline__ float fsig(float x) { return 1.0f / (1.0f + __expf(-x)); }
static __device__ __forceinline__ float ftanh(float x) {
    float e = __expf(2.0f * x);
    return 1.0f - 2.0f / (e + 1.0f);
}

// async global->LDS, 16B per lane. dst is the wave-uniform base; HW writes dst+lane*16.
static __device__ __forceinline__ void gll16(const float* src, float* ldsdst) {
    __builtin_amdgcn_global_load_lds(
        (const __attribute__((address_space(1))) void*)src,
        (__attribute__((address_space(3))) void*)ldsdst, 16, 0, 0);
}

// ------------------------- fused init: cnt=1 (NN), gstart=NN (NG+1) ----------
__global__ void k_init(int* cnt, int* gstart, int n, int ng1) {
    int i = blockIdx.x * 256 + threadIdx.x;
    if (i < n) cnt[i] = 1;
    if (i < ng1) gstart[i] = n;
}

// ------------------------- both weight transposes, one launch ----------------
__global__ void k_transpose2(const float* __restrict__ inA, float* __restrict__ outA,
                             const float* __restrict__ inB, float* __restrict__ outB) {
    int b = blockIdx.x, k = threadIdx.x;
    if (b < DD) outA[b * DD + k] = inA[k * DD + b];
    else { int n = b - DD; outB[n * DD + k] = inB[k * DD + n]; }
}

// ------------------------- GEMM: C[M,N] = A'[M,128] @ B[N,128]^T (+bias) ---------
// BK=32, 4 K-steps, double-buffered LDS, async global_load_lds staging, one
// barrier per K-step. XOR swizzle on the GLOBAL source column + same XOR on the
// ds_read index. k4 loop stays rolled (spill lesson, r2).
__global__ __launch_bounds__(256) void k_gemm(
    const float* __restrict__ A, const float* __restrict__ B, float* __restrict__ C,
    int M, int N, int t0, int clen, int rowsPerGraph,
    const float* __restrict__ bias1, const float* __restrict__ bias2)
{
    __shared__ float4 As[2][1024];
    __shared__ float4 Bs[2][1024];
    const int tid = threadIdx.x;
    const int wv = tid >> 6;
    const int m0 = blockIdx.x * 128, n0 = blockIdx.y * 128;
    const int tr = tid >> 4, tc = tid & 15;

    float acc[8][8];
    #pragma unroll
    for (int i = 0; i < 8; ++i)
        #pragma unroll
        for (int j = 0; j < 8; ++j) acc[i][j] = 0.f;

    auto stageA = [&](int buf, int k0) {
        #pragma unroll
        for (int it = 0; it < 4; ++it) {
            int f4 = it * 256 + tid;
            int r = f4 >> 3;
            int c4s = (f4 & 7) ^ (r & 7);
            int gr = m0 + r;
            float* dst = (float*)&As[buf][it * 256 + wv * 64];
            if (gr < M) {
                int flat = (gr / clen) * rowsPerGraph + t0 + (gr % clen);
                gll16(A + (size_t)flat * DD + k0 + c4s * 4, dst);
            }
        }
    };
    auto stageB = [&](int buf, int k0) {
        #pragma unroll
        for (int it = 0; it < 4; ++it) {
            int f4 = it * 256 + tid;
            int r = f4 >> 3;
            int c4s = (f4 & 7) ^ (r & 7);
            int gn = n0 + r;
            float* dst = (float*)&Bs[buf][it * 256 + wv * 64];
            if (gn < N) gll16(B + (size_t)gn * DD + k0 + c4s * 4, dst);
        }
    };

    stageA(0, 0); stageB(0, 0);
    __syncthreads();
    int buf = 0;
    const int axor = tr & 7;
    const int bxor = tc & 7;
    for (int ks = 0; ks < 4; ++ks) {
        if (ks < 3) { stageA(buf ^ 1, (ks + 1) * 32); stageB(buf ^ 1, (ks + 1) * 32); }
        const float4* Af = &As[buf][0];
        const float4* Bf = &Bs[buf][0];
        #pragma unroll 1
        for (int k4 = 0; k4 < 8; ++k4) {
            float4 a[8], b[8];
            #pragma unroll
            for (int i = 0; i < 8; ++i) a[i] = Af[(tr + i * 16) * 8 + (k4 ^ axor)];
            #pragma unroll
            for (int j = 0; j < 8; ++j) b[j] = Bf[(tc + j * 16) * 8 + (k4 ^ bxor)];
            #pragma unroll
            for (int i = 0; i < 8; ++i)
                #pragma unroll
                for (int j = 0; j < 8; ++j)
                    acc[i][j] += a[i].x * b[j].x + a[i].y * b[j].y + a[i].z * b[j].z + a[i].w * b[j].w;
        }
        __syncthreads();
        buf ^= 1;
    }

    #pragma unroll
    for (int i = 0; i < 8; ++i) {
        int gr = m0 + tr + i * 16;
        if (gr >= M) continue;
        #pragma unroll
        for (int j = 0; j < 8; ++j) {
            int gn = n0 + tc + j * 16;
            if (gn >= N) continue;
            float v = acc[i][j];
            if (bias1) v += bias1[gn];
            if (bias2) v += bias2[gn];
            C[(size_t)gr * N + gn] = v;
        }
    }
}

// ------------------------- alpha_s / alpha_d -------------------------
__global__ __launch_bounds__(256) void k_alpha(
    const float* __restrict__ h1, const float* __restrict__ a_src, const float* __restrict__ a_dst,
    float* __restrict__ as_out, float* __restrict__ ad_out, int n)
{
    int node = blockIdx.x * 4 + (threadIdx.x >> 6);
    int lane = threadIdx.x & 63;
    if (node >= n) return;
    float2 hv = *(const float2*)(h1 + (size_t)node * DD + 2 * lane);
    float2 av = *(const float2*)(a_src + 2 * lane);
    float2 dv = *(const float2*)(a_dst + 2 * lane);
    float s = hv.x * av.x + hv.y * av.y;
    float d = hv.x * dv.x + hv.y * dv.y;
    #pragma unroll
    for (int off = 1; off < 64; off <<= 1) {
        s += __shfl_xor(s, off);
        d += __shfl_xor(d, off);
    }
    if (lane == 0) { as_out[node] = s; ad_out[node] = d; }
}

// ------------------------- CSR build -------------------------
__global__ void k_hist(const int* __restrict__ ei, int* cnt, int E) {
    int e = blockIdx.x * 256 + threadIdx.x;
    if (e < E) atomicAdd(&cnt[ei[E + e]], 1);
}

// -------- parallel 3-phase scan (replaces single-block k_scan) --------
// scan1: block-local exclusive scan of cnt -> fill, block totals -> bsum
__global__ __launch_bounds__(256) void k_scan1(const int* __restrict__ cnt, int* __restrict__ fill,
                                               int* __restrict__ bsum, int n) {
    __shared__ int wsum[4];
    int tid = threadIdx.x, lane = tid & 63, wv = tid >> 6;
    int i = blockIdx.x * 256 + tid;
    int v = (i < n) ? cnt[i] : 0;
    int sc = v;
    #pragma unroll
    for (int off = 1; off < 64; off <<= 1) {
        int t = __shfl_up(sc, off);
        if (lane >= off) sc += t;
    }
    if (lane == 63) wsum[wv] = sc;
    __syncthreads();
    int base = 0;
    if (wv > 0) base += wsum[0];
    if (wv > 1) base += wsum[1];
    if (wv > 2) base += wsum[2];
    if (i < n) fill[i] = base + sc - v;   // block-exclusive
    if (tid == 255) bsum[blockIdx.x] = base + sc;
}
// scan2: exclusive scan of <=256 block totals, one block
__global__ __launch_bounds__(256) void k_scan2(int* __restrict__ bsum, int nb) {
    __shared__ int wsum[4];
    int tid = threadIdx.x, lane = tid & 63, wv = tid >> 6;
    int v = (tid < nb) ? bsum[tid] : 0;
    int sc = v;
    #pragma unroll
    for (int off = 1; off < 64; off <<= 1) {
        int t = __shfl_up(sc, off);
        if (lane >= off) sc += t;
    }
    if (lane == 63) wsum[wv] = sc;
    __syncthreads();
    int base = 0;
    if (wv > 0) base += wsum[0];
    if (wv > 1) base += wsum[1];
    if (wv > 2) base += wsum[2];
    if (tid < nb) bsum[tid] = base + sc - v;
}
// scan3: add block offsets; write rp and fill; rp[n] from last element
__global__ void k_scan3(const int* __restrict__ bsum, const int* __restrict__ cnt,
                        int* __restrict__ rp, int* __restrict__ fill, int n) {
    int i = blockIdx.x * 256 + threadIdx.x;
    if (i >= n) return;
    int v = fill[i] + bsum[blockIdx.x];
    rp[i] = v;
    fill[i] = v;
    if (i == n - 1) rp[n] = v + cnt[i];
}

__global__ void k_fill(const int* __restrict__ ei, int* fill, int* esrc, int E, int N) {
    int i = blockIdx.x * 256 + threadIdx.x;
    if (i < E) {
        int s = ei[i], d = ei[E + i];
        int slot = atomicAdd(&fill[d], 1);
        esrc[slot] = s;
    } else if (i < E + N) {
        int v = i - E;
        int slot = atomicAdd(&fill[v], 1);
        esrc[slot] = v;
    }
}

// ------------------------- dinv + graph bounds, one launch -------------------
__global__ void k_dinv_bounds(const int* __restrict__ rp, float* dinv,
                              const int* __restrict__ batch, int* gstart, int n) {
    int i = blockIdx.x * 256 + threadIdx.x;
    if (i >= n) return;
    dinv[i] = rsqrtf(fmaxf((float)(rp[i + 1] - rp[i]), 1.0f));
    int b = batch[i];
    if (i == 0 || batch[i - 1] != b) gstart[b] = i;
}

// ------------------------- GAT aggregation (wave per node) -------------------------
__global__ __launch_bounds__(256) void k_gat(
    const float* __restrict__ h1, const float* __restrict__ as, const float* __restrict__ ad_,
    const int* __restrict__ rp, const int* __restrict__ esrc,
    const float* __restrict__ bias, float* __restrict__ out, int n)
{
    __shared__ float2 ws_sh[4][CAP];   // .x = weight, .y = src (bits)
    int wv = threadIdx.x >> 6;
    int node = blockIdx.x * 4 + wv;
    int lane = threadIdx.x & 63;
    if (node >= n) return;
    int r0 = rp[node], r1 = rp[node + 1];
    int deg = r1 - r0;
    float adv = ad_[node];

    float sum = 0.f;
    for (int base = 0; base < deg; base += 64) {
        int idx = base + lane;
        float ex = 0.f;
        if (idx < deg) {
            int s = esrc[r0 + idx];
            float e = as[s] + adv;
            e = e > 0.f ? e : NEG_SLOPE * e;
            ex = __expf(e);
            if (idx < CAP) ws_sh[wv][idx] = make_float2(ex, __int_as_float(s));
        }
        sum += ex;
    }
    #pragma unroll
    for (int off = 1; off < 64; off <<= 1) sum += __shfl_xor(sum, off);
    float inv = 1.0f / sum;

    int nser = deg < CAP ? deg : CAP;
    int npad = (nser + 7) & ~7;        // deg>=1 (self loop) -> npad>=8
    for (int p = nser + lane; p < npad; p += 64)
        ws_sh[wv][p] = make_float2(0.f, __int_as_float(0));

    const float2* h1p = (const float2*)h1;
    float ax = 0.f, ay = 0.f;
    float wa[8]; float2 va[8];
    #pragma unroll
    for (int u = 0; u < 8; ++u) {
        float2 t = ws_sh[wv][u];
        wa[u] = t.x; va[u] = h1p[(size_t)__float_as_int(t.y) * 64 + lane];
    }
    #pragma unroll 1
    for (int idx = 8; idx < npad; idx += 8) {
        float wb[8]; float2 vb[8];
        #pragma unroll
        for (int u = 0; u < 8; ++u) {
            float2 t = ws_sh[wv][idx + u];
            wb[u] = t.x; vb[u] = h1p[(size_t)__float_as_int(t.y) * 64 + lane];
        }
        #pragma unroll
        for (int u = 0; u < 8; ++u) { ax += wa[u] * va[u].x; ay += wa[u] * va[u].y; }
        #pragma unroll
        for (int u = 0; u < 8; ++u) { wa[u] = wb[u]; va[u] = vb[u]; }
    }
    #pragma unroll
    for (int u = 0; u < 8; ++u) { ax += wa[u] * va[u].x; ay += wa[u] * va[u].y; }

    for (int j = r0 + CAP; j < r1; ++j) {
        int s = esrc[j];
        float e = as[s] + adv;
        e = e > 0.f ? e : NEG_SLOPE * e;
        float w = __expf(e);
        float2 hv = h1p[(size_t)s * 64 + lane];
        ax += w * hv.x;
        ay += w * hv.y;
    }
    float2 bv = *(const float2*)(bias + 2 * lane);
    float2 o;
    o.x = fmaxf(ax * inv + bv.x, 0.f);
    o.y = fmaxf(ay * inv + bv.y, 0.f);
    *(float2*)(out + (size_t)node * DD + 2 * lane) = o;
}

// ------------------------- GCN aggregation + scatter to padded ----------------
__global__ __launch_bounds__(256) void k_gcn(
    const float* __restrict__ h2, const float* __restrict__ dinv,
    const int* __restrict__ rp, const int* __restrict__ esrc,
    const float* __restrict__ bias, const int* __restrict__ batch,
    const int* __restrict__ gstart, float* __restrict__ padded, int n)
{
    __shared__ float2 cs_sh[4][CAP];
    int wv = threadIdx.x >> 6;
    int node = blockIdx.x * 4 + wv;
    int lane = threadIdx.x & 63;
    if (node >= n) return;
    int r0 = rp[node], r1 = rp[node + 1];
    int deg = r1 - r0;
    float dn = dinv[node];

    for (int base = 0; base < deg; base += 64) {
        int idx = base + lane;
        if (idx < deg && idx < CAP) {
            int s = esrc[r0 + idx];
            cs_sh[wv][idx] = make_float2(dinv[s], __int_as_float(s));
        }
    }
    int nser = deg < CAP ? deg : CAP;
    int npad = (nser + 7) & ~7;
    for (int p = nser + lane; p < npad; p += 64)
        cs_sh[wv][p] = make_float2(0.f, __int_as_float(0));

    const float2* h2p = (const float2*)h2;
    float ax = 0.f, ay = 0.f;
    float wa[8]; float2 va[8];
    #pragma unroll
    for (int u = 0; u < 8; ++u) {
        float2 t = cs_sh[wv][u];
        wa[u] = t.x; va[u] = h2p[(size_t)__float_as_int(t.y) * 64 + lane];
    }
    #pragma unroll 1
    for (int idx = 8; idx < npad; idx += 8) {
        float wb[8]; float2 vb[8];
        #pragma unroll
        for (int u = 0; u < 8; ++u) {
            float2 t = cs_sh[wv][idx + u];
            wb[u] = t.x; vb[u] = h2p[(size_t)__float_as_int(t.y) * 64 + lane];
        }
        #pragma unroll
        for (int u = 0; u < 8; ++u) { ax += wa[u] * va[u].x; ay += wa[u] * va[u].y; }
        #pragma unroll
        for (int u = 0; u < 8; ++u) { wa[u] = wb[u]; va[u] = vb[u]; }
    }
    #pragma unroll
    for (int u = 0; u < 8; ++u) { ax += wa[u] * va[u].x; ay += wa[u] * va[u].y; }

    for (int j = r0 + CAP; j < r1; ++j) {
        int s = esrc[j];
        float c = dinv[s];
        float2 hv = h2p[(size_t)s * 64 + lane];
        ax += c * hv.x;
        ay += c * hv.y;
    }
    int g = batch[node];
    if (g < 0 || g >= NG) return;
    int p = node - gstart[g];
    if (p < 0 || p >= TT) return;
    float2 bv = *(const float2*)(bias + 2 * lane);
    float2 o;
    o.x = fmaxf(ax * dn + bv.x, 0.f);
    o.y = fmaxf(ay * dn + bv.y, 0.f);
    *(float2*)(padded + ((size_t)g * TT + p) * DD + 2 * lane) = o;
}

// ------------------------- LSTM (block per graph, 4-way split-K) ----------------
// Phase A (all 512): 128 FMAs -> part[seg][qt*PSTRIDE+ub] (b128, consecutive lanes).
// Phase B (all 512): thread owns gate (q=tid&3, u=tid>>2): 4 part reads (2-way max
// with PSTRIDE=136), 1 exp (sign-folded sig/tanh), intra-quad DPP shuffles,
// redundant c/h per quad. Reads graph length from gstart directly.
__global__ __launch_bounds__(512) void k_lstm(
    const float* __restrict__ xw,     // [NG*clen, 512], includes b_ih+b_hh
    const float* __restrict__ Whh,    // [512,128]
    const int* __restrict__ gstart,
    float* __restrict__ hstate, float* __restrict__ cstate,
    float* __restrict__ grep, int t0, int clen)
{
    int g = blockIdx.x, tid = threadIdx.x;
    __shared__ __align__(16) float h_sh[DD];
    __shared__ __align__(16) float part[4][4 * PSTRIDE];

    const int seg = tid >> 7;       // phase-A role
    const int gq  = tid & 127;
    const int qt  = gq >> 5;        // part row block
    const int ub  = (gq & 31) * 4;
    const int u   = tid >> 2;       // phase-B: unit
    const int q   = tid & 3;        //          gate type
    const int lane = tid & 63;
    const int qbase = lane & ~3;

    float4 w[4][8];
    #pragma unroll
    for (int g4 = 0; g4 < 4; ++g4)
        #pragma unroll
        for (int i = 0; i < 8; ++i)
            w[g4][i] = *(const float4*)(Whh + (size_t)(4 * gq + g4) * DD + seg * 32 + i * 4);

    float creg = 0.f, hn = 0.f;
    if (t0 == 0) {
        if (tid < DD) h_sh[tid] = 0.f;
    } else {
        creg = cstate[g * DD + u];
        hn = hstate[g * DD + u];
        if (q == 0) h_sh[u] = hn;
    }
    int take = gstart[g + 1] - gstart[g] - 1;
    if (take < 0) take = 0;
    if (take > TT - 1) take = TT - 1;
    __syncthreads();

    const float* xb = xw + (size_t)g * clen * GH + q * DD + u;
    float xv = xb[0];

    for (int t = t0; t < t0 + clen; ++t) {
        int rel = t - t0;
        float xvn = 0.f;
        if (rel + 1 < clen) xvn = xb[(size_t)(rel + 1) * GH];   // full-step prefetch

        // phase A: partial gate dots over h[seg*32..+32]
        float4 hseg[8];
        #pragma unroll
        for (int i = 0; i < 8; ++i) hseg[i] = *(const float4*)(h_sh + seg * 32 + i * 4);
        float p0 = 0.f, p1 = 0.f, p2 = 0.f, p3 = 0.f;
        #pragma unroll
        for (int i = 0; i < 8; ++i) {
            float4 h4 = hseg[i];
            p0 += h4.x * w[0][i].x + h4.y * w[0][i].y + h4.z * w[0][i].z + h4.w * w[0][i].w;
            p1 += h4.x * w[1][i].x + h4.y * w[1][i].y + h4.z * w[1][i].z + h4.w * w[1][i].w;
            p2 += h4.x * w[2][i].x + h4.y * w[2][i].y + h4.z * w[2][i].z + h4.w * w[2][i].w;
            p3 += h4.x * w[3][i].x + h4.y * w[3][i].y + h4.z * w[3][i].z + h4.w * w[3][i].w;
        }
        *(float4*)(&part[seg][qt * PSTRIDE + ub]) = make_float4(p0, p1, p2, p3);
        __syncthreads();

        // phase B: full gate value + activation + quad combine
        int pidx = q * PSTRIDE + u;
        float G = xv + part[0][pidx] + part[1][pidx] + part[2][pidx] + part[3][pidx];
        float a = (q == 2) ? 2.f : -1.f;
        float e = __expf(a * G);
        float act = (q == 2) ? (1.f - 2.f / (e + 1.f)) : (1.f / (1.f + e));
        float ai = __shfl(act, qbase + 0);
        float af = __shfl(act, qbase + 1);
        float ag = __shfl(act, qbase + 2);
        float ao = __shfl(act, qbase + 3);
        creg = af * creg + ai * ag;
        hn = ao * ftanh(creg);
        if (q == 0) {
            h_sh[u] = hn;
            if (t == take) grep[g * DD + u] = hn;
        }
        xv = xvn;
        __syncthreads();
    }
    if (q == 0) { hstate[g * DD + u] = hn; cstate[g * DD + u] = creg; }
}

// ------------------------- FC -------------------------
__global__ void k_fc(const float* __restrict__ grep, const float* __restrict__ Wfc,
                     const float* __restrict__ bfc, float* __restrict__ out, int G) {
    int i = blockIdx.x * 256 + threadIdx.x;
    if (i >= G * 2) return;
    int g = i >> 1, o = i & 1;
    float acc = bfc[o];
    for (int d = 0; d < DD; ++d) acc += grep[g * DD + d] * Wfc[d * 2 + o];
    out[i] = acc;
}

// ------------------------- host launch -------------------------
extern "C" void kernel_launch(void* const* d_in, const int* in_sizes, int n_in,
                              void* d_out, int out_size, void* d_ws, size_t ws_size,
                              hipStream_t stream) {
    const float* x     = (const float*)d_in[0];
    const int*   ei    = (const int*)d_in[1];
    const int*   batch = (const int*)d_in[2];
    const float* Wgat  = (const float*)d_in[3];
    const float* a_src = (const float*)d_in[4];
    const float* a_dst = (const float*)d_in[5];
    const float* b_gat = (const float*)d_in[6];
    const float* Wgcn  = (const float*)d_in[7];
    const float* b_gcn = (const float*)d_in[8];
    const float* Wih   = (const float*)d_in[9];   // [512,128]
    const float* Whh   = (const float*)d_in[10];  // [512,128]
    const float* b_ih  = (const float*)d_in[11];
    const float* b_hh  = (const float*)d_in[12];
    const float* Wfc   = (const float*)d_in[13];
    const float* b_fc  = (const float*)d_in[14];
    float* out = (float*)d_out;

    float* ws = (float*)d_ws;
    const size_t F = (size_t)NN * DD;  // 6.4M floats
    float* h1 = ws;
    float* h2 = ws;
    float* xwChunk = ws;
    float* gato   = ws + F;
    float* padded = ws + F;
    size_t off = 2 * F;
    float* alpha_s = ws + off; off += 50048;
    float* alpha_d = ws + off; off += 50048;
    float* dinv    = ws + off; off += 50048;
    int*   cnt     = (int*)(ws + off); off += 50048;
    int*   rp      = (int*)(ws + off); off += 50056;
    int*   fill    = (int*)(ws + off); off += 50048;
    int*   esrc    = (int*)(ws + off); off += 850048;
    int*   bsum    = (int*)(ws + off); off += 256;
    int*   gstart  = (int*)(ws + off); off += 256;
    float* grep    = ws + off; off += 32000;
    float* hstate  = ws + off; off += 32000;
    float* cstate  = ws + off; off += 32000;
    float* WgatT   = ws + off; off += 16384;
    float* WgcnT   = ws + off; off += 16384;
    const size_t xwBigFloats = (size_t)NG * TT * GH;   // 25.6M floats
    float* xwBig = ws + off;
    const bool big = ws_size >= (off + xwBigFloats) * sizeof(float);

    // 1. transpose both weights
    k_transpose2<<<256, 128, 0, stream>>>(Wgat, WgatT, Wgcn, WgcnT);

    // 2. h1 = x @ W_gat
    k_gemm<<<dim3(391, 1), 256, 0, stream>>>(x, WgatT, h1, NN, DD, 0, TT, TT, nullptr, nullptr);

    // 3. alpha
    k_alpha<<<12500, 256, 0, stream>>>(h1, a_src, a_dst, alpha_s, alpha_d, NN);

    // 4. CSR build (parallel 3-phase scan) + graph bounds
    k_init<<<196, 256, 0, stream>>>(cnt, gstart, NN, NG + 1);
    k_hist<<<3125, 256, 0, stream>>>(ei, cnt, NE);
    k_scan1<<<196, 256, 0, stream>>>(cnt, fill, bsum, NN);
    k_scan2<<<1, 256, 0, stream>>>(bsum, 196);
    k_scan3<<<196, 256, 0, stream>>>(bsum, cnt, rp, fill, NN);
    k_fill<<<3321, 256, 0, stream>>>(ei, fill, esrc, NE, NN);
    k_dinv_bounds<<<196, 256, 0, stream>>>(rp, dinv, batch, gstart, NN);

    // 5. GAT aggregation -> gato
    k_gat<<<12500, 256, 0, stream>>>(h1, alpha_s, alpha_d, rp, esrc, b_gat, gato, NN);

    // 6. h2 = gato @ W_gcn
    k_gemm<<<dim3(391, 1), 256, 0, stream>>>(gato, WgcnT, h2, NN, DD, 0, TT, TT, nullptr, nullptr);

    // 7. GCN aggregation -> padded
    k_gcn<<<12500, 256, 0, stream>>>(h2, dinv, rp, esrc, b_gcn, batch, gstart, padded, NN);

    // 8. LSTM
    if (big) {
        k_gemm<<<dim3(391, 4), 256, 0, stream>>>(padded, Wih, xwBig, NG * TT, GH,
                                                 0, TT, TT, b_ih, b_hh);
        k_lstm<<<NG, 512, 0, stream>>>(xwBig, Whh, gstart, hstate, cstate, grep, 0, TT);
    } else {
        for (int c = 0; c < NCHUNK; ++c) {
            int t0 = c * CLEN;
            k_gemm<<<dim3(98, 4), 256, 0, stream>>>(padded, Wih, xwChunk, NG * CLEN, GH,
                                                    t0, CLEN, TT, b_ih, b_hh);
            k_lstm<<<NG, 512, 0, stream>>>(xwChunk, Whh, gstart, hstate, cstate, grep, t0, CLEN);
        }
    }

    // 9. FC
    k_fc<<<2, 256, 0, stream>>>(grep, Wfc, b_fc, out, NG);
}

// Round 12
// 577.210 us; speedup vs baseline: 1.2156x; 1.0926x over previous
//
#include <hip/hip_runtime.h>
#include <cstddef>

#define NN 50000      // nodes
#define NE 800000     // edges (without self loops)
#define NG 250        // graphs
#define TT 200        // nodes per graph / LSTM steps
#define DD 128        // feature dim
#define GH 512        // 4*LSTM_H
#define NEG_SLOPE 0.2f
#define NCHUNK 4
#define CLEN 50       // TT / NCHUNK (fallback path)
#define CAP 128       // per-wave LDS edge cache
#define PSTRIDE 136   // 136 % 32 == 8 -> phase-B reads max 2-way (free)

static __device__ __forceinline__ float fsig(float x) { return 1.0f / (1.0f + __expf(-x)); }
static __device__ __forceinline__ float ftanh(float x) {
    float e = __expf(2.0f * x);
    return 1.0f - 2.0f / (e + 1.0f);
}
// bf16 helpers (manual, RNE)
static __device__ __forceinline__ unsigned short f2bf(float f) {
    unsigned int u = __float_as_uint(f);
    return (unsigned short)((u + 0x7fffu + ((u >> 16) & 1u)) >> 16);
}

// async global->LDS, 16B per lane. dst is the wave-uniform base; HW writes dst+lane*16.
static __device__ __forceinline__ void gll16(const float* src, float* ldsdst) {
    __builtin_amdgcn_global_load_lds(
        (const __attribute__((address_space(1))) void*)src,
        (__attribute__((address_space(3))) void*)ldsdst, 16, 0, 0);
}

// ------------------------- fused init: cnt=1 (NN), gstart=NN (NG+1) ----------
__global__ void k_init(int* cnt, int* gstart, int n, int ng1) {
    int i = blockIdx.x * 256 + threadIdx.x;
    if (i < n) cnt[i] = 1;
    if (i < ng1) gstart[i] = n;
}

// ------------------------- both weight transposes, one launch ----------------
__global__ void k_transpose2(const float* __restrict__ inA, float* __restrict__ outA,
                             const float* __restrict__ inB, float* __restrict__ outB) {
    int b = blockIdx.x, k = threadIdx.x;
    if (b < DD) outA[b * DD + k] = inA[k * DD + b];
    else { int n = b - DD; outB[n * DD + k] = inB[k * DD + n]; }
}

// ------------------------- GEMM: C[M,N] = A'[M,128] @ B[N,128]^T (+bias) ---------
// BK=32, 4 K-steps, double-buffered LDS, async global_load_lds staging, one
// barrier per K-step. XOR swizzle on the GLOBAL source column + same XOR on the
// ds_read index. k4 loop stays rolled (spill lesson, r2).
// Optional: bf16 output (Cbf) and fused alpha row-dots (requires N==128, grid.y==1).
__global__ __launch_bounds__(256) void k_gemm(
    const float* __restrict__ A, const float* __restrict__ B, float* __restrict__ C,
    int M, int N, int t0, int clen, int rowsPerGraph,
    const float* __restrict__ bias1, const float* __restrict__ bias2,
    unsigned short* __restrict__ Cbf,
    float* __restrict__ as_out, float* __restrict__ ad_out,
    const float* __restrict__ a_src, const float* __restrict__ a_dst)
{
    __shared__ float4 As[2][1024];
    __shared__ float4 Bs[2][1024];
    const int tid = threadIdx.x;
    const int wv = tid >> 6;
    const int m0 = blockIdx.x * 128, n0 = blockIdx.y * 128;
    const int tr = tid >> 4, tc = tid & 15;

    float acc[8][8];
    #pragma unroll
    for (int i = 0; i < 8; ++i)
        #pragma unroll
        for (int j = 0; j < 8; ++j) acc[i][j] = 0.f;

    auto stageA = [&](int buf, int k0) {
        #pragma unroll
        for (int it = 0; it < 4; ++it) {
            int f4 = it * 256 + tid;
            int r = f4 >> 3;
            int c4s = (f4 & 7) ^ (r & 7);
            int gr = m0 + r;
            float* dst = (float*)&As[buf][it * 256 + wv * 64];
            if (gr < M) {
                int flat = (gr / clen) * rowsPerGraph + t0 + (gr % clen);
                gll16(A + (size_t)flat * DD + k0 + c4s * 4, dst);
            }
        }
    };
    auto stageB = [&](int buf, int k0) {
        #pragma unroll
        for (int it = 0; it < 4; ++it) {
            int f4 = it * 256 + tid;
            int r = f4 >> 3;
            int c4s = (f4 & 7) ^ (r & 7);
            int gn = n0 + r;
            float* dst = (float*)&Bs[buf][it * 256 + wv * 64];
            if (gn < N) gll16(B + (size_t)gn * DD + k0 + c4s * 4, dst);
        }
    };

    stageA(0, 0); stageB(0, 0);
    __syncthreads();
    int buf = 0;
    const int axor = tr & 7;
    const int bxor = tc & 7;
    for (int ks = 0; ks < 4; ++ks) {
        if (ks < 3) { stageA(buf ^ 1, (ks + 1) * 32); stageB(buf ^ 1, (ks + 1) * 32); }
        const float4* Af = &As[buf][0];
        const float4* Bf = &Bs[buf][0];
        #pragma unroll 1
        for (int k4 = 0; k4 < 8; ++k4) {
            float4 a[8], b[8];
            #pragma unroll
            for (int i = 0; i < 8; ++i) a[i] = Af[(tr + i * 16) * 8 + (k4 ^ axor)];
            #pragma unroll
            for (int j = 0; j < 8; ++j) b[j] = Bf[(tc + j * 16) * 8 + (k4 ^ bxor)];
            #pragma unroll
            for (int i = 0; i < 8; ++i)
                #pragma unroll
                for (int j = 0; j < 8; ++j)
                    acc[i][j] += a[i].x * b[j].x + a[i].y * b[j].y + a[i].z * b[j].z + a[i].w * b[j].w;
        }
        __syncthreads();
        buf ^= 1;
    }

    // fused alpha row-dots (h1 gemm only: N==128, one y-block holds full rows)
    if (as_out) {
        float asv[8], adv[8];
        #pragma unroll
        for (int j = 0; j < 8; ++j) { asv[j] = a_src[tc + 16 * j]; adv[j] = a_dst[tc + 16 * j]; }
        #pragma unroll
        for (int i = 0; i < 8; ++i) {
            float s = 0.f, d = 0.f;
            #pragma unroll
            for (int j = 0; j < 8; ++j) { s += acc[i][j] * asv[j]; d += acc[i][j] * adv[j]; }
            #pragma unroll
            for (int off = 1; off < 16; off <<= 1) { s += __shfl_xor(s, off); d += __shfl_xor(d, off); }
            int gr = m0 + tr + i * 16;
            if (tc == 0 && gr < M) { as_out[gr] = s; ad_out[gr] = d; }
        }
    }

    #pragma unroll
    for (int i = 0; i < 8; ++i) {
        int gr = m0 + tr + i * 16;
        if (gr >= M) continue;
        #pragma unroll
        for (int j = 0; j < 8; ++j) {
            int gn = n0 + tc + j * 16;
            if (gn >= N) continue;
            float v = acc[i][j];
            if (bias1) v += bias1[gn];
            if (bias2) v += bias2[gn];
            if (Cbf) Cbf[(size_t)gr * N + gn] = f2bf(v);
            else     C[(size_t)gr * N + gn] = v;
        }
    }
}

// ------------------------- CSR build -------------------------
__global__ void k_hist(const int* __restrict__ ei, int* cnt, int E) {
    int e = blockIdx.x * 256 + threadIdx.x;
    if (e < E) atomicAdd(&cnt[ei[E + e]], 1);
}

// -------- parallel 3-phase scan --------
__global__ __launch_bounds__(256) void k_scan1(const int* __restrict__ cnt, int* __restrict__ fill,
                                               int* __restrict__ bsum, int n) {
    __shared__ int wsum[4];
    int tid = threadIdx.x, lane = tid & 63, wv = tid >> 6;
    int i = blockIdx.x * 256 + tid;
    int v = (i < n) ? cnt[i] : 0;
    int sc = v;
    #pragma unroll
    for (int off = 1; off < 64; off <<= 1) {
        int t = __shfl_up(sc, off);
        if (lane >= off) sc += t;
    }
    if (lane == 63) wsum[wv] = sc;
    __syncthreads();
    int base = 0;
    if (wv > 0) base += wsum[0];
    if (wv > 1) base += wsum[1];
    if (wv > 2) base += wsum[2];
    if (i < n) fill[i] = base + sc - v;   // block-exclusive
    if (tid == 255) bsum[blockIdx.x] = base + sc;
}
__global__ __launch_bounds__(256) void k_scan2(int* __restrict__ bsum, int nb) {
    __shared__ int wsum[4];
    int tid = threadIdx.x, lane = tid & 63, wv = tid >> 6;
    int v = (tid < nb) ? bsum[tid] : 0;
    int sc = v;
    #pragma unroll
    for (int off = 1; off < 64; off <<= 1) {
        int t = __shfl_up(sc, off);
        if (lane >= off) sc += t;
    }
    if (lane == 63) wsum[wv] = sc;
    __syncthreads();
    int base = 0;
    if (wv > 0) base += wsum[0];
    if (wv > 1) base += wsum[1];
    if (wv > 2) base += wsum[2];
    if (tid < nb) bsum[tid] = base + sc - v;
}
// scan3 + dinv (deg == cnt[i]) + graph bounds, one launch
__global__ void k_scan3(const int* __restrict__ bsum, const int* __restrict__ cnt,
                        int* __restrict__ rp, int* __restrict__ fill,
                        float* __restrict__ dinv, const int* __restrict__ batch,
                        int* __restrict__ gstart, int n) {
    int i = blockIdx.x * 256 + threadIdx.x;
    if (i >= n) return;
    int v = fill[i] + bsum[blockIdx.x];
    rp[i] = v;
    fill[i] = v;
    if (i == n - 1) rp[n] = v + cnt[i];
    dinv[i] = rsqrtf(fmaxf((float)cnt[i], 1.0f));
    int b = batch[i];
    if (i == 0 || batch[i - 1] != b) gstart[b] = i;
}

__global__ void k_fill(const int* __restrict__ ei, int* fill, int* esrc, int E, int N) {
    int i = blockIdx.x * 256 + threadIdx.x;
    if (i < E) {
        int s = ei[i], d = ei[E + i];
        int slot = atomicAdd(&fill[d], 1);
        esrc[slot] = s;
    } else if (i < E + N) {
        int v = i - E;
        int slot = atomicAdd(&fill[v], 1);
        esrc[slot] = v;
    }
}

// ------------------------- GAT aggregation (wave per node, bf16 h gather) -------
__global__ __launch_bounds__(256) void k_gat(
    const unsigned int* __restrict__ h1b,   // [NN][64] packed 2xbf16
    const float* __restrict__ as, const float* __restrict__ ad_,
    const int* __restrict__ rp, const int* __restrict__ esrc,
    const float* __restrict__ bias, float* __restrict__ out, int n)
{
    __shared__ float2 ws_sh[4][CAP];   // .x = weight, .y = src (bits)
    int wv = threadIdx.x >> 6;
    int node = blockIdx.x * 4 + wv;
    int lane = threadIdx.x & 63;
    if (node >= n) return;
    int r0 = rp[node], r1 = rp[node + 1];
    int deg = r1 - r0;
    float adv = ad_[node];

    float sum = 0.f;
    for (int base = 0; base < deg; base += 64) {
        int idx = base + lane;
        float ex = 0.f;
        if (idx < deg) {
            int s = esrc[r0 + idx];
            float e = as[s] + adv;
            e = e > 0.f ? e : NEG_SLOPE * e;
            ex = __expf(e);
            if (idx < CAP) ws_sh[wv][idx] = make_float2(ex, __int_as_float(s));
        }
        sum += ex;
    }
    #pragma unroll
    for (int off = 1; off < 64; off <<= 1) sum += __shfl_xor(sum, off);
    float inv = 1.0f / sum;

    int nser = deg < CAP ? deg : CAP;
    int npad = (nser + 7) & ~7;
    for (int p = nser + lane; p < npad; p += 64)
        ws_sh[wv][p] = make_float2(0.f, __int_as_float(0));

    float ax = 0.f, ay = 0.f;
    float wa[8]; unsigned int va[8];
    #pragma unroll
    for (int u = 0; u < 8; ++u) {
        float2 t = ws_sh[wv][u];
        wa[u] = t.x; va[u] = h1b[(size_t)__float_as_int(t.y) * 64 + lane];
    }
    #pragma unroll 1
    for (int idx = 8; idx < npad; idx += 8) {
        float wb[8]; unsigned int vb[8];
        #pragma unroll
        for (int u = 0; u < 8; ++u) {
            float2 t = ws_sh[wv][idx + u];
            wb[u] = t.x; vb[u] = h1b[(size_t)__float_as_int(t.y) * 64 + lane];
        }
        #pragma unroll
        for (int u = 0; u < 8; ++u) {
            ax += wa[u] * __uint_as_float(va[u] << 16);
            ay += wa[u] * __uint_as_float(va[u] & 0xffff0000u);
        }
        #pragma unroll
        for (int u = 0; u < 8; ++u) { wa[u] = wb[u]; va[u] = vb[u]; }
    }
    #pragma unroll
    for (int u = 0; u < 8; ++u) {
        ax += wa[u] * __uint_as_float(va[u] << 16);
        ay += wa[u] * __uint_as_float(va[u] & 0xffff0000u);
    }

    for (int j = r0 + CAP; j < r1; ++j) {   // rare overflow path
        int s = esrc[j];
        float e = as[s] + adv;
        e = e > 0.f ? e : NEG_SLOPE * e;
        float w = __expf(e);
        unsigned int v = h1b[(size_t)s * 64 + lane];
        ax += w * __uint_as_float(v << 16);
        ay += w * __uint_as_float(v & 0xffff0000u);
    }
    float2 bv = *(const float2*)(bias + 2 * lane);
    float2 o;
    o.x = fmaxf(ax * inv + bv.x, 0.f);
    o.y = fmaxf(ay * inv + bv.y, 0.f);
    *(float2*)(out + (size_t)node * DD + 2 * lane) = o;
}

// ------------------------- GCN aggregation + scatter to padded (bf16 gather) ----
__global__ __launch_bounds__(256) void k_gcn(
    const unsigned int* __restrict__ h2b, const float* __restrict__ dinv,
    const int* __restrict__ rp, const int* __restrict__ esrc,
    const float* __restrict__ bias, const int* __restrict__ batch,
    const int* __restrict__ gstart, float* __restrict__ padded, int n)
{
    __shared__ float2 cs_sh[4][CAP];
    int wv = threadIdx.x >> 6;
    int node = blockIdx.x * 4 + wv;
    int lane = threadIdx.x & 63;
    if (node >= n) return;
    int r0 = rp[node], r1 = rp[node + 1];
    int deg = r1 - r0;
    float dn = dinv[node];

    for (int base = 0; base < deg; base += 64) {
        int idx = base + lane;
        if (idx < deg && idx < CAP) {
            int s = esrc[r0 + idx];
            cs_sh[wv][idx] = make_float2(dinv[s], __int_as_float(s));
        }
    }
    int nser = deg < CAP ? deg : CAP;
    int npad = (nser + 7) & ~7;
    for (int p = nser + lane; p < npad; p += 64)
        cs_sh[wv][p] = make_float2(0.f, __int_as_float(0));
    __syncthreads();   // cs_sh filled by strided loop above (wave-local but keep ordering simple)

    float ax = 0.f, ay = 0.f;
    float wa[8]; unsigned int va[8];
    #pragma unroll
    for (int u = 0; u < 8; ++u) {
        float2 t = cs_sh[wv][u];
        wa[u] = t.x; va[u] = h2b[(size_t)__float_as_int(t.y) * 64 + lane];
    }
    #pragma unroll 1
    for (int idx = 8; idx < npad; idx += 8) {
        float wb[8]; unsigned int vb[8];
        #pragma unroll
        for (int u = 0; u < 8; ++u) {
            float2 t = cs_sh[wv][idx + u];
            wb[u] = t.x; vb[u] = h2b[(size_t)__float_as_int(t.y) * 64 + lane];
        }
        #pragma unroll
        for (int u = 0; u < 8; ++u) {
            ax += wa[u] * __uint_as_float(va[u] << 16);
            ay += wa[u] * __uint_as_float(va[u] & 0xffff0000u);
        }
        #pragma unroll
        for (int u = 0; u < 8; ++u) { wa[u] = wb[u]; va[u] = vb[u]; }
    }
    #pragma unroll
    for (int u = 0; u < 8; ++u) {
        ax += wa[u] * __uint_as_float(va[u] << 16);
        ay += wa[u] * __uint_as_float(va[u] & 0xffff0000u);
    }

    for (int j = r0 + CAP; j < r1; ++j) {
        int s = esrc[j];
        float c = dinv[s];
        unsigned int v = h2b[(size_t)s * 64 + lane];
        ax += c * __uint_as_float(v << 16);
        ay += c * __uint_as_float(v & 0xffff0000u);
    }
    int g = batch[node];
    if (g < 0 || g >= NG) return;
    int p = node - gstart[g];
    if (p < 0 || p >= TT) return;
    float2 bv = *(const float2*)(bias + 2 * lane);
    float2 o;
    o.x = fmaxf(ax * dn + bv.x, 0.f);
    o.y = fmaxf(ay * dn + bv.y, 0.f);
    *(float2*)(padded + ((size_t)g * TT + p) * DD + 2 * lane) = o;
}

// ------------------------- LSTM (block per graph, 4-way split-K) ----------------
__global__ __launch_bounds__(512) void k_lstm(
    const float* __restrict__ xw,     // [NG*clen, 512], includes b_ih+b_hh
    const float* __restrict__ Whh,    // [512,128]
    const int* __restrict__ gstart,
    float* __restrict__ hstate, float* __restrict__ cstate,
    float* __restrict__ grep, int t0, int clen)
{
    int g = blockIdx.x, tid = threadIdx.x;
    __shared__ __align__(16) float h_sh[DD];
    __shared__ __align__(16) float part[4][4 * PSTRIDE];

    const int seg = tid >> 7;
    const int gq  = tid & 127;
    const int qt  = gq >> 5;
    const int ub  = (gq & 31) * 4;
    const int u   = tid >> 2;
    const int q   = tid & 3;
    const int lane = tid & 63;
    const int qbase = lane & ~3;

    float4 w[4][8];
    #pragma unroll
    for (int g4 = 0; g4 < 4; ++g4)
        #pragma unroll
        for (int i = 0; i < 8; ++i)
            w[g4][i] = *(const float4*)(Whh + (size_t)(4 * gq + g4) * DD + seg * 32 + i * 4);

    float creg = 0.f, hn = 0.f;
    if (t0 == 0) {
        if (tid < DD) h_sh[tid] = 0.f;
    } else {
        creg = cstate[g * DD + u];
        hn = hstate[g * DD + u];
        if (q == 0) h_sh[u] = hn;
    }
    int take = gstart[g + 1] - gstart[g] - 1;
    if (take < 0) take = 0;
    if (take > TT - 1) take = TT - 1;
    __syncthreads();

    const float* xb = xw + (size_t)g * clen * GH + q * DD + u;
    float xv = xb[0];

    for (int t = t0; t < t0 + clen; ++t) {
        int rel = t - t0;
        float xvn = 0.f;
        if (rel + 1 < clen) xvn = xb[(size_t)(rel + 1) * GH];

        float4 hseg[8];
        #pragma unroll
        for (int i = 0; i < 8; ++i) hseg[i] = *(const float4*)(h_sh + seg * 32 + i * 4);
        float p0 = 0.f, p1 = 0.f, p2 = 0.f, p3 = 0.f;
        #pragma unroll
        for (int i = 0; i < 8; ++i) {
            float4 h4 = hseg[i];
            p0 += h4.x * w[0][i].x + h4.y * w[0][i].y + h4.z * w[0][i].z + h4.w * w[0][i].w;
            p1 += h4.x * w[1][i].x + h4.y * w[1][i].y + h4.z * w[1][i].z + h4.w * w[1][i].w;
            p2 += h4.x * w[2][i].x + h4.y * w[2][i].y + h4.z * w[2][i].z + h4.w * w[2][i].w;
            p3 += h4.x * w[3][i].x + h4.y * w[3][i].y + h4.z * w[3][i].z + h4.w * w[3][i].w;
        }
        *(float4*)(&part[seg][qt * PSTRIDE + ub]) = make_float4(p0, p1, p2, p3);
        __syncthreads();

        int pidx = q * PSTRIDE + u;
        float G = xv + part[0][pidx] + part[1][pidx] + part[2][pidx] + part[3][pidx];
        float a = (q == 2) ? 2.f : -1.f;
        float e = __expf(a * G);
        float act = (q == 2) ? (1.f - 2.f / (e + 1.f)) : (1.f / (1.f + e));
        float ai = __shfl(act, qbase + 0);
        float af = __shfl(act, qbase + 1);
        float ag = __shfl(act, qbase + 2);
        float ao = __shfl(act, qbase + 3);
        creg = af * creg + ai * ag;
        hn = ao * ftanh(creg);
        if (q == 0) {
            h_sh[u] = hn;
            if (t == take) grep[g * DD + u] = hn;
        }
        xv = xvn;
        __syncthreads();
    }
    if (q == 0) { hstate[g * DD + u] = hn; cstate[g * DD + u] = creg; }
}

// ------------------------- FC -------------------------
__global__ void k_fc(const float* __restrict__ grep, const float* __restrict__ Wfc,
                     const float* __restrict__ bfc, float* __restrict__ out, int G) {
    int i = blockIdx.x * 256 + threadIdx.x;
    if (i >= G * 2) return;
    int g = i >> 1, o = i & 1;
    float acc = bfc[o];
    for (int d = 0; d < DD; ++d) acc += grep[g * DD + d] * Wfc[d * 2 + o];
    out[i] = acc;
}

// ------------------------- host launch -------------------------
extern "C" void kernel_launch(void* const* d_in, const int* in_sizes, int n_in,
                              void* d_out, int out_size, void* d_ws, size_t ws_size,
                              hipStream_t stream) {
    const float* x     = (const float*)d_in[0];
    const int*   ei    = (const int*)d_in[1];
    const int*   batch = (const int*)d_in[2];
    const float* Wgat  = (const float*)d_in[3];
    const float* a_src = (const float*)d_in[4];
    const float* a_dst = (const float*)d_in[5];
    const float* b_gat = (const float*)d_in[6];
    const float* Wgcn  = (const float*)d_in[7];
    const float* b_gcn = (const float*)d_in[8];
    const float* Wih   = (const float*)d_in[9];   // [512,128]
    const float* Whh   = (const float*)d_in[10];  // [512,128]
    const float* b_ih  = (const float*)d_in[11];
    const float* b_hh  = (const float*)d_in[12];
    const float* Wfc   = (const float*)d_in[13];
    const float* b_fc  = (const float*)d_in[14];
    float* out = (float*)d_out;

    float* ws = (float*)d_ws;
    const size_t F = (size_t)NN * DD;  // 6.4M floats
    // Region 0: h1b (bf16, 3.2M fl) -> h2b (bf16) -> xwChunk (fallback)
    unsigned short* h1b = (unsigned short*)ws;
    unsigned short* h2b = (unsigned short*)ws;
    float* xwChunk = ws;
    // Region B: gato -> padded
    float* gato   = ws + F;
    float* padded = ws + F;
    size_t off = 2 * F;
    float* alpha_s = ws + off; off += 50048;
    float* alpha_d = ws + off; off += 50048;
    float* dinv    = ws + off; off += 50048;
    int*   cnt     = (int*)(ws + off); off += 50048;
    int*   rp      = (int*)(ws + off); off += 50056;
    int*   fill    = (int*)(ws + off); off += 50048;
    int*   esrc    = (int*)(ws + off); off += 850048;
    int*   bsum    = (int*)(ws + off); off += 256;
    int*   gstart  = (int*)(ws + off); off += 256;
    float* grep    = ws + off; off += 32000;
    float* hstate  = ws + off; off += 32000;
    float* cstate  = ws + off; off += 32000;
    float* WgatT   = ws + off; off += 16384;
    float* WgcnT   = ws + off; off += 16384;
    const size_t xwBigFloats = (size_t)NG * TT * GH;   // 25.6M floats
    float* xwBig = ws + off;
    const bool big = ws_size >= (off + xwBigFloats) * sizeof(float);

    // 1. transpose both weights
    k_transpose2<<<256, 128, 0, stream>>>(Wgat, WgatT, Wgcn, WgcnT);

    // 2. h1b = bf16(x @ W_gat), alpha fused in epilogue
    k_gemm<<<dim3(391, 1), 256, 0, stream>>>(x, WgatT, nullptr, NN, DD, 0, TT, TT,
                                             nullptr, nullptr, h1b,
                                             alpha_s, alpha_d, a_src, a_dst);

    // 3. CSR build (parallel scan; dinv+bounds fused into scan3)
    k_init<<<196, 256, 0, stream>>>(cnt, gstart, NN, NG + 1);
    k_hist<<<3125, 256, 0, stream>>>(ei, cnt, NE);
    k_scan1<<<196, 256, 0, stream>>>(cnt, fill, bsum, NN);
    k_scan2<<<1, 256, 0, stream>>>(bsum, 196);
    k_scan3<<<196, 256, 0, stream>>>(bsum, cnt, rp, fill, dinv, batch, gstart, NN);
    k_fill<<<3321, 256, 0, stream>>>(ei, fill, esrc, NE, NN);

    // 4. GAT aggregation -> gato (fp32)
    k_gat<<<12500, 256, 0, stream>>>((const unsigned int*)h1b, alpha_s, alpha_d,
                                     rp, esrc, b_gat, gato, NN);

    // 5. h2b = bf16(gato @ W_gcn)
    k_gemm<<<dim3(391, 1), 256, 0, stream>>>(gato, WgcnT, nullptr, NN, DD, 0, TT, TT,
                                             nullptr, nullptr, h2b,
                                             nullptr, nullptr, nullptr, nullptr);

    // 6. GCN aggregation -> padded (fp32)
    k_gcn<<<12500, 256, 0, stream>>>((const unsigned int*)h2b, dinv, rp, esrc,
                                     b_gcn, batch, gstart, padded, NN);

    // 7. LSTM
    if (big) {
        k_gemm<<<dim3(391, 4), 256, 0, stream>>>(padded, Wih, xwBig, NG * TT, GH,
                                                 0, TT, TT, b_ih, b_hh,
                                                 nullptr, nullptr, nullptr, nullptr, nullptr);
        k_lstm<<<NG, 512, 0, stream>>>(xwBig, Whh, gstart, hstate, cstate, grep, 0, TT);
    } else {
        for (int c = 0; c < NCHUNK; ++c) {
            int t0 = c * CLEN;
            k_gemm<<<dim3(98, 4), 256, 0, stream>>>(padded, Wih, xwChunk, NG * CLEN, GH,
                                                    t0, CLEN, TT, b_ih, b_hh,
                                                    nullptr, nullptr, nullptr, nullptr, nullptr);
            k_lstm<<<NG, 512, 0, stream>>>(xwChunk, Whh, gstart, hstate, cstate, grep, t0, CLEN);
        }
    }

    // 8. FC
    k_fc<<<2, 256, 0, stream>>>(grep, Wfc, b_fc, out, NG);
}